// Round 1
// baseline (2112.514 us; speedup 1.0000x reference)
//
#include <hip/hip_runtime.h>
#include <cstdint>
#include <cstddef>

#define HID 128
#define N_USERS 100000
#define N_JOBS  50000
#define N_EDGES 2000000
#define N_LABELS 500000

// ---------------------------------------------------------------------------
// Histogram of edge endpoints (for CSR build)
// ---------------------------------------------------------------------------
__global__ void hist_kernel(const int* __restrict__ src, const int* __restrict__ dst,
                            int nE, int* __restrict__ cnt_u, int* __restrict__ cnt_j) {
    int i = blockIdx.x * blockDim.x + threadIdx.x;
    int stride = gridDim.x * blockDim.x;
    for (; i < nE; i += stride) {
        atomicAdd(&cnt_j[dst[i]], 1);
        atomicAdd(&cnt_u[src[i]], 1);
    }
}

// ---------------------------------------------------------------------------
// Single-block exclusive scan (n up to ~100k, chunked Hillis-Steele)
// Writes off[0..n] and a copy into cur[0..n-1] (scatter cursors).
// ---------------------------------------------------------------------------
__global__ __launch_bounds__(1024) void scan_kernel(const int* __restrict__ cnt,
                                                    int* __restrict__ off,
                                                    int* __restrict__ cur, int n) {
    __shared__ int smem[1024];
    __shared__ int carry_s;
    if (threadIdx.x == 0) carry_s = 0;
    __syncthreads();
    for (int base = 0; base < n; base += 1024) {
        int i = base + (int)threadIdx.x;
        int v = (i < n) ? cnt[i] : 0;
        smem[threadIdx.x] = v;
        __syncthreads();
        #pragma unroll
        for (int s = 1; s < 1024; s <<= 1) {
            int t = (threadIdx.x >= (unsigned)s) ? smem[threadIdx.x - s] : 0;
            __syncthreads();
            smem[threadIdx.x] += t;
            __syncthreads();
        }
        int excl = smem[threadIdx.x] - v;
        int c = carry_s;                     // all threads read old carry
        if (i < n) { off[i] = c + excl; cur[i] = c + excl; }
        __syncthreads();
        if (threadIdx.x == 0) carry_s = c + smem[1023];
        __syncthreads();
    }
    if (threadIdx.x == 0) off[n] = carry_s;
}

// ---------------------------------------------------------------------------
// Scatter edges into both CSR value arrays using fetch-add cursors
// ---------------------------------------------------------------------------
__global__ void scatter_kernel(const int* __restrict__ src, const int* __restrict__ dst,
                               int nE, int* __restrict__ cur_u, int* __restrict__ cur_j,
                               int* __restrict__ vals_u, int* __restrict__ vals_j) {
    int i = blockIdx.x * blockDim.x + threadIdx.x;
    int stride = gridDim.x * blockDim.x;
    for (; i < nE; i += stride) {
        int s = src[i], d = dst[i];
        int pj = atomicAdd(&cur_j[d], 1);
        vals_j[pj] = s;
        int pu = atomicAdd(&cur_u[s], 1);
        vals_u[pu] = d;
    }
}

// ---------------------------------------------------------------------------
// Mean aggregation: one wave (64 lanes) per destination node; lane owns 2 of
// the 128 features. Gather of 512B rows is fully coalesced per edge.
// ---------------------------------------------------------------------------
__global__ __launch_bounds__(64) void aggregate_kernel(const float* __restrict__ x,
                                                       const int* __restrict__ off,
                                                       const int* __restrict__ vals,
                                                       float* __restrict__ out, int nDst) {
    int d = blockIdx.x;
    if (d >= nDst) return;
    int lane = threadIdx.x;
    int beg = off[d], end = off[d + 1];
    float a0 = 0.f, a1 = 0.f;
    for (int e = beg; e < end; ++e) {
        int s = vals[e];
        const float2 v = *reinterpret_cast<const float2*>(x + (size_t)s * HID + lane * 2);
        a0 += v.x; a1 += v.y;
    }
    float inv = 1.0f / fmaxf((float)(end - beg), 1.0f);
    float2 r; r.x = a0 * inv; r.y = a1 * inv;
    *reinterpret_cast<float2*>(out + (size_t)d * HID + lane * 2) = r;
}

// ---------------------------------------------------------------------------
// Encoder GEMM: out = relu(BN(X @ W^T + b)).  X:[M,K], W:[128,K].
// 64x128 tile per block (256 thr), K-step 16, 4x8 accums per thread.
// ---------------------------------------------------------------------------
__global__ __launch_bounds__(256) void encoder_kernel(
    const float* __restrict__ X, const float* __restrict__ W,
    const float* __restrict__ b, const float* __restrict__ gamma,
    const float* __restrict__ beta, const float* __restrict__ mean,
    const float* __restrict__ var, float* __restrict__ out, int M, int K) {
    __shared__ float Xs[16][68];    // [kk][row]
    __shared__ float Ws[16][132];   // [kk][col]
    int tid = threadIdx.x;
    int tx = tid & 15, ty = tid >> 4;
    int m0 = blockIdx.x * 64;
    float acc[4][8] = {};
    for (int k0 = 0; k0 < K; k0 += 16) {
        {   // X tile: thread loads 1 float4
            int row = tid >> 2; int kk = (tid & 3) * 4;
            int gr = m0 + row;
            float4 v = make_float4(0.f, 0.f, 0.f, 0.f);
            if (gr < M) v = *reinterpret_cast<const float4*>(X + (size_t)gr * K + k0 + kk);
            Xs[kk + 0][row] = v.x; Xs[kk + 1][row] = v.y;
            Xs[kk + 2][row] = v.z; Xs[kk + 3][row] = v.w;
        }
        {   // W tile: thread loads 2 float4 (one col, 8 k)
            int col = tid >> 1; int kk = (tid & 1) * 8;
            const float4 v0 = *reinterpret_cast<const float4*>(W + (size_t)col * K + k0 + kk);
            const float4 v1 = *reinterpret_cast<const float4*>(W + (size_t)col * K + k0 + kk + 4);
            Ws[kk + 0][col] = v0.x; Ws[kk + 1][col] = v0.y;
            Ws[kk + 2][col] = v0.z; Ws[kk + 3][col] = v0.w;
            Ws[kk + 4][col] = v1.x; Ws[kk + 5][col] = v1.y;
            Ws[kk + 6][col] = v1.z; Ws[kk + 7][col] = v1.w;
        }
        __syncthreads();
        #pragma unroll
        for (int kk = 0; kk < 16; ++kk) {
            float4 xv = *reinterpret_cast<const float4*>(&Xs[kk][ty * 4]);
            float4 w0 = *reinterpret_cast<const float4*>(&Ws[kk][tx * 8]);
            float4 w1 = *reinterpret_cast<const float4*>(&Ws[kk][tx * 8 + 4]);
            float xr[4] = {xv.x, xv.y, xv.z, xv.w};
            float wc[8] = {w0.x, w0.y, w0.z, w0.w, w1.x, w1.y, w1.z, w1.w};
            #pragma unroll
            for (int r = 0; r < 4; ++r)
                #pragma unroll
                for (int c = 0; c < 8; ++c)
                    acc[r][c] += xr[r] * wc[c];
        }
        __syncthreads();
    }
    // epilogue: BN(eval) + ReLU
    float s_[8], sh_[8];
    #pragma unroll
    for (int c = 0; c < 8; ++c) {
        int gc = tx * 8 + c;
        float s = gamma[gc] * rsqrtf(var[gc] + 1e-5f);
        s_[c] = s;
        sh_[c] = (b[gc] - mean[gc]) * s + beta[gc];
    }
    #pragma unroll
    for (int r = 0; r < 4; ++r) {
        int gr = m0 + ty * 4 + r;
        if (gr < M) {
            float v[8];
            #pragma unroll
            for (int c = 0; c < 8; ++c) v[c] = fmaxf(acc[r][c] * s_[c] + sh_[c], 0.f);
            float4 o0 = make_float4(v[0], v[1], v[2], v[3]);
            float4 o1 = make_float4(v[4], v[5], v[6], v[7]);
            *reinterpret_cast<float4*>(out + (size_t)gr * HID + tx * 8) = o0;
            *reinterpret_cast<float4*>(out + (size_t)gr * HID + tx * 8 + 4) = o1;
        }
    }
}

// ---------------------------------------------------------------------------
// SAGE dual GEMM: out = [relu](A @ WA^T + bl + B @ WB^T).  A,B:[M,128],
// WA,WB:[128,128]. Same tiling as encoder, two K=128 phases.
// ---------------------------------------------------------------------------
__global__ __launch_bounds__(256) void sage_kernel(
    const float* __restrict__ A, const float* __restrict__ Bm,
    const float* __restrict__ WA, const float* __restrict__ WB,
    const float* __restrict__ bl, float* __restrict__ out, int M, int doRelu) {
    __shared__ float Xs[16][68];
    __shared__ float Ws[16][132];
    int tid = threadIdx.x;
    int tx = tid & 15, ty = tid >> 4;
    int m0 = blockIdx.x * 64;
    float acc[4][8] = {};
    for (int phase = 0; phase < 2; ++phase) {
        const float* X = phase ? Bm : A;
        const float* W = phase ? WB : WA;
        for (int k0 = 0; k0 < 128; k0 += 16) {
            {
                int row = tid >> 2; int kk = (tid & 3) * 4;
                int gr = m0 + row;
                float4 v = make_float4(0.f, 0.f, 0.f, 0.f);
                if (gr < M) v = *reinterpret_cast<const float4*>(X + (size_t)gr * 128 + k0 + kk);
                Xs[kk + 0][row] = v.x; Xs[kk + 1][row] = v.y;
                Xs[kk + 2][row] = v.z; Xs[kk + 3][row] = v.w;
            }
            {
                int col = tid >> 1; int kk = (tid & 1) * 8;
                const float4 v0 = *reinterpret_cast<const float4*>(W + (size_t)col * 128 + k0 + kk);
                const float4 v1 = *reinterpret_cast<const float4*>(W + (size_t)col * 128 + k0 + kk + 4);
                Ws[kk + 0][col] = v0.x; Ws[kk + 1][col] = v0.y;
                Ws[kk + 2][col] = v0.z; Ws[kk + 3][col] = v0.w;
                Ws[kk + 4][col] = v1.x; Ws[kk + 5][col] = v1.y;
                Ws[kk + 6][col] = v1.z; Ws[kk + 7][col] = v1.w;
            }
            __syncthreads();
            #pragma unroll
            for (int kk = 0; kk < 16; ++kk) {
                float4 xv = *reinterpret_cast<const float4*>(&Xs[kk][ty * 4]);
                float4 w0 = *reinterpret_cast<const float4*>(&Ws[kk][tx * 8]);
                float4 w1 = *reinterpret_cast<const float4*>(&Ws[kk][tx * 8 + 4]);
                float xr[4] = {xv.x, xv.y, xv.z, xv.w};
                float wc[8] = {w0.x, w0.y, w0.z, w0.w, w1.x, w1.y, w1.z, w1.w};
                #pragma unroll
                for (int r = 0; r < 4; ++r)
                    #pragma unroll
                    for (int c = 0; c < 8; ++c)
                        acc[r][c] += xr[r] * wc[c];
            }
            __syncthreads();
        }
    }
    float bl_[8];
    #pragma unroll
    for (int c = 0; c < 8; ++c) bl_[c] = bl[tx * 8 + c];
    #pragma unroll
    for (int r = 0; r < 4; ++r) {
        int gr = m0 + ty * 4 + r;
        if (gr < M) {
            float v[8];
            #pragma unroll
            for (int c = 0; c < 8; ++c) {
                float x = acc[r][c] + bl_[c];
                v[c] = doRelu ? fmaxf(x, 0.f) : x;
            }
            float4 o0 = make_float4(v[0], v[1], v[2], v[3]);
            float4 o1 = make_float4(v[4], v[5], v[6], v[7]);
            *reinterpret_cast<float4*>(out + (size_t)gr * HID + tx * 8) = o0;
            *reinterpret_cast<float4*>(out + (size_t)gr * HID + tx * 8 + 4) = o1;
        }
    }
}

// ---------------------------------------------------------------------------
// Link readout: one wave per label edge, dot over 128 features
// ---------------------------------------------------------------------------
__global__ __launch_bounds__(256) void dot_kernel(const float* __restrict__ U,
                                                  const float* __restrict__ J,
                                                  const int* __restrict__ ls,
                                                  const int* __restrict__ ld,
                                                  float* __restrict__ out, int nL) {
    int w = (int)((blockIdx.x * blockDim.x + threadIdx.x) >> 6);
    int lane = threadIdx.x & 63;
    if (w >= nL) return;
    int a = ls[w], c = ld[w];
    float2 uv = *reinterpret_cast<const float2*>(U + (size_t)a * HID + lane * 2);
    float2 jv = *reinterpret_cast<const float2*>(J + (size_t)c * HID + lane * 2);
    float p = uv.x * jv.x + uv.y * jv.y;
    #pragma unroll
    for (int s = 32; s > 0; s >>= 1) p += __shfl_xor(p, s, 64);
    if (lane == 0) out[w] = p;
}

// ---------------------------------------------------------------------------
extern "C" void kernel_launch(void* const* d_in, const int* in_sizes, int n_in,
                              void* d_out, int out_size, void* d_ws, size_t ws_size,
                              hipStream_t stream) {
    const float* user_x     = (const float*)d_in[0];
    const float* job_x      = (const float*)d_in[1];
    const float* user_W     = (const float*)d_in[2];
    const float* user_b     = (const float*)d_in[3];
    const float* user_gamma = (const float*)d_in[4];
    const float* user_beta  = (const float*)d_in[5];
    const float* user_mean  = (const float*)d_in[6];
    const float* user_var   = (const float*)d_in[7];
    const float* job_W      = (const float*)d_in[8];
    const float* job_b      = (const float*)d_in[9];
    const float* job_gamma  = (const float*)d_in[10];
    const float* job_beta   = (const float*)d_in[11];
    const float* job_mean   = (const float*)d_in[12];
    const float* job_var    = (const float*)d_in[13];
    const float* l1_rates_Wl = (const float*)d_in[14];
    const float* l1_rates_Wr = (const float*)d_in[15];
    const float* l1_rev_Wl   = (const float*)d_in[16];
    const float* l1_rev_Wr   = (const float*)d_in[17];
    const float* l2_rates_Wl = (const float*)d_in[18];
    const float* l2_rates_Wr = (const float*)d_in[19];
    const float* l2_rev_Wl   = (const float*)d_in[20];
    const float* l2_rev_Wr   = (const float*)d_in[21];
    const float* l1_rates_bl = (const float*)d_in[22];
    const float* l1_rev_bl   = (const float*)d_in[23];
    const float* l2_rates_bl = (const float*)d_in[24];
    const float* l2_rev_bl   = (const float*)d_in[25];
    const int* rates_src = (const int*)d_in[26];
    const int* rates_dst = (const int*)d_in[27];
    const int* label_src = (const int*)d_in[28];
    const int* label_dst = (const int*)d_in[29];

    // ---- workspace layout ----
    char* ws = (char*)d_ws;
    size_t o = 0;
    auto alloc = [&](size_t bytes) -> void* {
        void* p = ws + o;
        o = (o + bytes + 511) & ~(size_t)511;
        return p;
    };
    float* u    = (float*)alloc((size_t)N_USERS * HID * 4);
    float* j    = (float*)alloc((size_t)N_JOBS  * HID * 4);
    float* u1   = (float*)alloc((size_t)N_USERS * HID * 4);
    float* j1   = (float*)alloc((size_t)N_JOBS  * HID * 4);
    float* aggU = (float*)alloc((size_t)N_USERS * HID * 4);
    float* aggJ = (float*)alloc((size_t)N_JOBS  * HID * 4);
    int* vals_j = (int*)alloc((size_t)N_EDGES * 4);
    int* vals_u = (int*)alloc((size_t)N_EDGES * 4);
    int* cnt_j  = (int*)alloc((size_t)N_JOBS * 4);
    int* cnt_u  = (int*)alloc((size_t)N_USERS * 4);
    int* off_j  = (int*)alloc((size_t)(N_JOBS + 1) * 4);
    int* off_u  = (int*)alloc((size_t)(N_USERS + 1) * 4);
    int* cur_j  = (int*)alloc((size_t)N_JOBS * 4);
    int* cur_u  = (int*)alloc((size_t)N_USERS * 4);
    float* u2 = u;  // u dead after u1; reuse
    float* j2 = j;  // j dead after j1; reuse
    (void)ws_size; (void)n_in; (void)in_sizes; (void)out_size;

    // ---- CSR build (shared by both layers) ----
    hipMemsetAsync(cnt_j, 0, (size_t)N_JOBS * 4, stream);
    hipMemsetAsync(cnt_u, 0, (size_t)N_USERS * 4, stream);
    hist_kernel<<<2048, 256, 0, stream>>>(rates_src, rates_dst, N_EDGES, cnt_u, cnt_j);
    scan_kernel<<<1, 1024, 0, stream>>>(cnt_j, off_j, cur_j, N_JOBS);
    scan_kernel<<<1, 1024, 0, stream>>>(cnt_u, off_u, cur_u, N_USERS);
    scatter_kernel<<<2048, 256, 0, stream>>>(rates_src, rates_dst, N_EDGES,
                                             cur_u, cur_j, vals_u, vals_j);

    // ---- encoders ----
    encoder_kernel<<<(N_USERS + 63) / 64, 256, 0, stream>>>(
        user_x, user_W, user_b, user_gamma, user_beta, user_mean, user_var, u, N_USERS, 512);
    encoder_kernel<<<(N_JOBS + 63) / 64, 256, 0, stream>>>(
        job_x, job_W, job_b, job_gamma, job_beta, job_mean, job_var, j, N_JOBS, 768);

    // ---- SAGE layer 1 ----
    aggregate_kernel<<<N_JOBS, 64, 0, stream>>>(u, off_j, vals_j, aggJ, N_JOBS);
    sage_kernel<<<(N_JOBS + 63) / 64, 256, 0, stream>>>(
        aggJ, j, l1_rates_Wl, l1_rates_Wr, l1_rates_bl, j1, N_JOBS, 1);
    aggregate_kernel<<<N_USERS, 64, 0, stream>>>(j, off_u, vals_u, aggU, N_USERS);
    sage_kernel<<<(N_USERS + 63) / 64, 256, 0, stream>>>(
        aggU, u, l1_rev_Wl, l1_rev_Wr, l1_rev_bl, u1, N_USERS, 1);

    // ---- SAGE layer 2 (no relu) ----
    aggregate_kernel<<<N_JOBS, 64, 0, stream>>>(u1, off_j, vals_j, aggJ, N_JOBS);
    sage_kernel<<<(N_JOBS + 63) / 64, 256, 0, stream>>>(
        aggJ, j1, l2_rates_Wl, l2_rates_Wr, l2_rates_bl, j2, N_JOBS, 0);
    aggregate_kernel<<<N_USERS, 64, 0, stream>>>(j1, off_u, vals_u, aggU, N_USERS);
    sage_kernel<<<(N_USERS + 63) / 64, 256, 0, stream>>>(
        aggU, u1, l2_rev_Wl, l2_rev_Wr, l2_rev_bl, u2, N_USERS, 0);

    // ---- link readout ----
    dot_kernel<<<(N_LABELS * 64 + 255) / 256, 256, 0, stream>>>(
        u2, j2, label_src, label_dst, (float*)d_out, N_LABELS);
}

// Round 2
// 1373.141 us; speedup vs baseline: 1.5385x; 1.5385x over previous
//
#include <hip/hip_runtime.h>
#include <cstdint>
#include <cstddef>

#define HID 128
#define N_USERS 100000
#define N_JOBS  50000
#define N_EDGES 2000000
#define N_LABELS 500000
#define SCHUNK 1024

typedef __attribute__((ext_vector_type(8))) short short8;
typedef __attribute__((ext_vector_type(4))) float f32x4;

__device__ __forceinline__ unsigned short f2b(float f) {
    union { float f; unsigned u; } v; v.f = f;
    unsigned r = v.u + 0x7FFFu + ((v.u >> 16) & 1u);   // RNE to bf16
    return (unsigned short)(r >> 16);
}
__device__ __forceinline__ float b2f(unsigned h) {
    union { unsigned u; float f; } v; v.u = h << 16;
    return v.f;
}

// ---------------------------------------------------------------------------
// CSR build: histogram
// ---------------------------------------------------------------------------
__global__ void hist_kernel(const int* __restrict__ src, const int* __restrict__ dst,
                            int nE, int* __restrict__ cnt_u, int* __restrict__ cnt_j) {
    int i = blockIdx.x * blockDim.x + threadIdx.x;
    int stride = gridDim.x * blockDim.x;
    for (; i < nE; i += stride) {
        atomicAdd(&cnt_j[dst[i]], 1);
        atomicAdd(&cnt_u[src[i]], 1);
    }
}

// ---- hierarchical exclusive scan (3 kernels) ----
__global__ __launch_bounds__(256) void scan_blocksum(const int* __restrict__ cnt,
                                                     int* __restrict__ partial, int n) {
    int b = blockIdx.x, t = threadIdx.x;
    int base = b * SCHUNK;
    int s = 0;
    #pragma unroll
    for (int i = 0; i < 4; ++i) {
        int idx = base + t + i * 256;
        if (idx < n) s += cnt[idx];
    }
    #pragma unroll
    for (int d = 32; d; d >>= 1) s += __shfl_xor(s, d, 64);
    __shared__ int wsum[4];
    if ((t & 63) == 0) wsum[t >> 6] = s;
    __syncthreads();
    if (t == 0) partial[b] = wsum[0] + wsum[1] + wsum[2] + wsum[3];
}

__global__ __launch_bounds__(128) void scan_level2(int* __restrict__ pj, int nbj,
                                                   int* __restrict__ pu, int nbu) {
    int* p = blockIdx.x ? pu : pj;
    int nb = blockIdx.x ? nbu : nbj;
    int t = threadIdx.x;
    __shared__ int sm[128];
    int v = (t < nb) ? p[t] : 0;
    sm[t] = v;
    __syncthreads();
    for (int d = 1; d < 128; d <<= 1) {
        int q = (t >= d) ? sm[t - d] : 0;
        __syncthreads();
        sm[t] += q;
        __syncthreads();
    }
    if (t < nb) p[t] = sm[t] - v;   // exclusive
}

__global__ __launch_bounds__(256) void scan_final(const int* __restrict__ cnt,
                                                  const int* __restrict__ partial,
                                                  int* __restrict__ off, int* __restrict__ cur,
                                                  int n) {
    int b = blockIdx.x, t = threadIdx.x;
    int lane = t & 63, wid = t >> 6;
    int idx0 = b * SCHUNK + t * 4;
    int c[4];
    #pragma unroll
    for (int i = 0; i < 4; ++i) c[i] = (idx0 + i < n) ? cnt[idx0 + i] : 0;
    int tsum = c[0] + c[1] + c[2] + c[3];
    int sc = tsum;
    #pragma unroll
    for (int d = 1; d < 64; d <<= 1) {
        int q = __shfl_up(sc, d, 64);
        if (lane >= d) sc += q;
    }
    __shared__ int wtot[4];
    if (lane == 63) wtot[wid] = sc;
    __syncthreads();
    int woff = 0;
    for (int w = 0; w < wid; ++w) woff += wtot[w];
    int run = woff + sc - tsum + partial[b];
    #pragma unroll
    for (int i = 0; i < 4; ++i) {
        int idx = idx0 + i;
        if (idx < n) { off[idx] = run; cur[idx] = run; run += c[i]; }
    }
    if (b == 0 && t == 0) off[n] = N_EDGES;
}

// ---------------------------------------------------------------------------
// Scatter edges into both CSR value arrays
// ---------------------------------------------------------------------------
__global__ void scatter_kernel(const int* __restrict__ src, const int* __restrict__ dst,
                               int nE, int* __restrict__ cur_u, int* __restrict__ cur_j,
                               int* __restrict__ vals_u, int* __restrict__ vals_j) {
    int i = blockIdx.x * blockDim.x + threadIdx.x;
    int stride = gridDim.x * blockDim.x;
    for (; i < nE; i += stride) {
        int s = src[i], d = dst[i];
        int pj = atomicAdd(&cur_j[d], 1);
        vals_j[pj] = s;
        int pu = atomicAdd(&cur_u[s], 1);
        vals_u[pu] = d;
    }
}

// ---------------------------------------------------------------------------
// Mean aggregation over bf16 features: one wave per destination node
// ---------------------------------------------------------------------------
__global__ __launch_bounds__(256) void aggregate_bf16(const unsigned short* __restrict__ x,
                                                      const int* __restrict__ off,
                                                      const int* __restrict__ vals,
                                                      unsigned short* __restrict__ out, int nDst) {
    int node = blockIdx.x * 4 + (threadIdx.x >> 6);
    if (node >= nDst) return;
    int lane = threadIdx.x & 63;
    int beg = off[node], end = off[node + 1];
    float a0 = 0.f, a1 = 0.f;
    int e = beg;
    for (; e + 1 < end; e += 2) {
        int s0 = vals[e], s1 = vals[e + 1];
        unsigned v0 = *reinterpret_cast<const unsigned*>(x + (size_t)s0 * HID + lane * 2);
        unsigned v1 = *reinterpret_cast<const unsigned*>(x + (size_t)s1 * HID + lane * 2);
        a0 += b2f(v0 & 0xffffu) + b2f(v1 & 0xffffu);
        a1 += b2f(v0 >> 16) + b2f(v1 >> 16);
    }
    if (e < end) {
        unsigned v0 = *reinterpret_cast<const unsigned*>(x + (size_t)vals[e] * HID + lane * 2);
        a0 += b2f(v0 & 0xffffu);
        a1 += b2f(v0 >> 16);
    }
    float inv = 1.0f / fmaxf((float)(end - beg), 1.0f);
    unsigned r = (unsigned)f2b(a0 * inv) | ((unsigned)f2b(a1 * inv) << 16);
    *reinterpret_cast<unsigned*>(out + (size_t)node * HID + lane * 2) = r;
}

// ---------------------------------------------------------------------------
// Encoder: out_bf16 = relu(BN(X @ W^T + b)).  X:[M,K] fp32, W:[128,K] fp32.
// 128x128 tile, BK=64 bf16, MFMA 16x16x32, XOR-swizzled LDS.
// ---------------------------------------------------------------------------
__global__ __launch_bounds__(256) void encoder_mfma(
    const float* __restrict__ X, const float* __restrict__ W,
    const float* __restrict__ bias, const float* __restrict__ gamma,
    const float* __restrict__ beta, const float* __restrict__ mean,
    const float* __restrict__ var, unsigned short* __restrict__ out, int M, int K) {
    __shared__ char lds[32768];              // A: [0,16K), B: [16K,32K)
    int tid = threadIdx.x;
    int m0 = blockIdx.x * 128;
    int wid = tid >> 6, lane = tid & 63;
    int wr = wid >> 1, wc = wid & 1;
    int lrow = lane & 15, lgrp = lane >> 4;
    f32x4 acc[4][4];
    #pragma unroll
    for (int m = 0; m < 4; ++m)
        #pragma unroll
        for (int n = 0; n < 4; ++n) acc[m][n] = (f32x4){0.f, 0.f, 0.f, 0.f};

    for (int k0 = 0; k0 < K; k0 += 64) {
        #pragma unroll
        for (int i = 0; i < 8; ++i) {        // A tile: 2048 float4, 8/thread
            int f = tid + i * 256;
            int row = f >> 4, fi = f & 15;
            int gr = m0 + row;
            float4 v = make_float4(0.f, 0.f, 0.f, 0.f);
            if (gr < M) v = *reinterpret_cast<const float4*>(X + (size_t)gr * K + k0 + fi * 4);
            unsigned lo = (unsigned)f2b(v.x) | ((unsigned)f2b(v.y) << 16);
            unsigned hi = (unsigned)f2b(v.z) | ((unsigned)f2b(v.w) << 16);
            int slot = fi >> 1, rest = (fi & 1) * 8;
            int o = row * 128 + (((slot ^ (row & 7)) << 4) | rest);
            *reinterpret_cast<uint2*>(lds + o) = make_uint2(lo, hi);
        }
        #pragma unroll
        for (int i = 0; i < 8; ++i) {        // W tile
            int f = tid + i * 256;
            int row = f >> 4, fi = f & 15;
            float4 v = *reinterpret_cast<const float4*>(W + (size_t)row * K + k0 + fi * 4);
            unsigned lo = (unsigned)f2b(v.x) | ((unsigned)f2b(v.y) << 16);
            unsigned hi = (unsigned)f2b(v.z) | ((unsigned)f2b(v.w) << 16);
            int slot = fi >> 1, rest = (fi & 1) * 8;
            int o = 16384 + row * 128 + (((slot ^ (row & 7)) << 4) | rest);
            *reinterpret_cast<uint2*>(lds + o) = make_uint2(lo, hi);
        }
        __syncthreads();
        #pragma unroll
        for (int ks = 0; ks < 2; ++ks) {
            short8 af[4], bf[4];
            #pragma unroll
            for (int m = 0; m < 4; ++m) {
                int row = wr * 64 + m * 16 + lrow;
                int slot = ks * 4 + lgrp;
                af[m] = *reinterpret_cast<const short8*>(lds + row * 128 + ((slot ^ (row & 7)) << 4));
            }
            #pragma unroll
            for (int n = 0; n < 4; ++n) {
                int row = wc * 64 + n * 16 + lrow;
                int slot = ks * 4 + lgrp;
                bf[n] = *reinterpret_cast<const short8*>(lds + 16384 + row * 128 + ((slot ^ (row & 7)) << 4));
            }
            #pragma unroll
            for (int m = 0; m < 4; ++m)
                #pragma unroll
                for (int n = 0; n < 4; ++n)
                    acc[m][n] = __builtin_amdgcn_mfma_f32_16x16x32_bf16(af[m], bf[n], acc[m][n], 0, 0, 0);
        }
        __syncthreads();
    }
    float sc[4], sh[4]; int col[4];
    #pragma unroll
    for (int n = 0; n < 4; ++n) {
        int gc = wc * 64 + n * 16 + lrow;
        col[n] = gc;
        float s = gamma[gc] * rsqrtf(var[gc] + 1e-5f);
        sc[n] = s;
        sh[n] = (bias[gc] - mean[gc]) * s + beta[gc];
    }
    #pragma unroll
    for (int m = 0; m < 4; ++m)
        #pragma unroll
        for (int j = 0; j < 4; ++j) {
            int row = m0 + wr * 64 + m * 16 + lgrp * 4 + j;
            if (row < M) {
                #pragma unroll
                for (int n = 0; n < 4; ++n) {
                    float v = fmaxf(acc[m][n][j] * sc[n] + sh[n], 0.f);
                    out[(size_t)row * HID + col[n]] = f2b(v);
                }
            }
        }
}

// ---------------------------------------------------------------------------
// SAGE dual GEMM: out = [relu](Aagg @ WA^T + bl + Bx @ WB^T)
// Aagg,Bx: [M,128] bf16. WA,WB: [128,128] fp32. out bf16 or fp32.
// ---------------------------------------------------------------------------
__global__ __launch_bounds__(256) void sage_mfma(
    const unsigned short* __restrict__ Aagg, const unsigned short* __restrict__ Bx,
    const float* __restrict__ WA, const float* __restrict__ WB,
    const float* __restrict__ bl, void* __restrict__ outv,
    int M, int doRelu, int outF32) {
    __shared__ char lds[32768];
    int tid = threadIdx.x;
    int m0 = blockIdx.x * 128;
    int wid = tid >> 6, lane = tid & 63;
    int wr = wid >> 1, wc = wid & 1;
    int lrow = lane & 15, lgrp = lane >> 4;
    f32x4 acc[4][4];
    #pragma unroll
    for (int m = 0; m < 4; ++m)
        #pragma unroll
        for (int n = 0; n < 4; ++n) acc[m][n] = (f32x4){0.f, 0.f, 0.f, 0.f};

    for (int s = 0; s < 4; ++s) {
        const unsigned short* src = (s < 2) ? Aagg : Bx;
        const float* Wp = (s < 2) ? WA : WB;
        int k0 = (s & 1) * 64;
        #pragma unroll
        for (int i = 0; i < 4; ++i) {        // A tile: bf16 source, 1024x16B units
            int u = tid + i * 256;
            int row = u >> 3, slot = u & 7;
            int gr = m0 + row;
            uint4 v = make_uint4(0, 0, 0, 0);
            if (gr < M) v = *reinterpret_cast<const uint4*>(src + (size_t)gr * HID + k0 + slot * 8);
            *reinterpret_cast<uint4*>(lds + row * 128 + ((slot ^ (row & 7)) << 4)) = v;
        }
        #pragma unroll
        for (int i = 0; i < 8; ++i) {        // W tile: fp32 -> bf16
            int f = tid + i * 256;
            int row = f >> 4, fi = f & 15;
            float4 v = *reinterpret_cast<const float4*>(Wp + (size_t)row * HID + k0 + fi * 4);
            unsigned lo = (unsigned)f2b(v.x) | ((unsigned)f2b(v.y) << 16);
            unsigned hi = (unsigned)f2b(v.z) | ((unsigned)f2b(v.w) << 16);
            int slot = fi >> 1, rest = (fi & 1) * 8;
            int o = 16384 + row * 128 + (((slot ^ (row & 7)) << 4) | rest);
            *reinterpret_cast<uint2*>(lds + o) = make_uint2(lo, hi);
        }
        __syncthreads();
        #pragma unroll
        for (int ks = 0; ks < 2; ++ks) {
            short8 af[4], bf[4];
            #pragma unroll
            for (int m = 0; m < 4; ++m) {
                int row = wr * 64 + m * 16 + lrow;
                int slot = ks * 4 + lgrp;
                af[m] = *reinterpret_cast<const short8*>(lds + row * 128 + ((slot ^ (row & 7)) << 4));
            }
            #pragma unroll
            for (int n = 0; n < 4; ++n) {
                int row = wc * 64 + n * 16 + lrow;
                int slot = ks * 4 + lgrp;
                bf[n] = *reinterpret_cast<const short8*>(lds + 16384 + row * 128 + ((slot ^ (row & 7)) << 4));
            }
            #pragma unroll
            for (int m = 0; m < 4; ++m)
                #pragma unroll
                for (int n = 0; n < 4; ++n)
                    acc[m][n] = __builtin_amdgcn_mfma_f32_16x16x32_bf16(af[m], bf[n], acc[m][n], 0, 0, 0);
        }
        __syncthreads();
    }
    float blv[4]; int col[4];
    #pragma unroll
    for (int n = 0; n < 4; ++n) { col[n] = wc * 64 + n * 16 + lrow; blv[n] = bl[col[n]]; }
    #pragma unroll
    for (int m = 0; m < 4; ++m)
        #pragma unroll
        for (int j = 0; j < 4; ++j) {
            int row = m0 + wr * 64 + m * 16 + lgrp * 4 + j;
            if (row < M) {
                #pragma unroll
                for (int n = 0; n < 4; ++n) {
                    float v = acc[m][n][j] + blv[n];
                    if (doRelu) v = fmaxf(v, 0.f);
                    if (outF32) ((float*)outv)[(size_t)row * HID + col[n]] = v;
                    else        ((unsigned short*)outv)[(size_t)row * HID + col[n]] = f2b(v);
                }
            }
        }
}

// ---------------------------------------------------------------------------
// Link readout: one wave per label edge, fp32 inputs
// ---------------------------------------------------------------------------
__global__ __launch_bounds__(256) void dot_kernel(const float* __restrict__ U,
                                                  const float* __restrict__ J,
                                                  const int* __restrict__ ls,
                                                  const int* __restrict__ ld,
                                                  float* __restrict__ out, int nL) {
    int w = (int)((blockIdx.x * blockDim.x + threadIdx.x) >> 6);
    int lane = threadIdx.x & 63;
    if (w >= nL) return;
    int a = ls[w], c = ld[w];
    float2 uv = *reinterpret_cast<const float2*>(U + (size_t)a * HID + lane * 2);
    float2 jv = *reinterpret_cast<const float2*>(J + (size_t)c * HID + lane * 2);
    float p = uv.x * jv.x + uv.y * jv.y;
    #pragma unroll
    for (int s = 32; s > 0; s >>= 1) p += __shfl_xor(p, s, 64);
    if (lane == 0) out[w] = p;
}

// ---------------------------------------------------------------------------
extern "C" void kernel_launch(void* const* d_in, const int* in_sizes, int n_in,
                              void* d_out, int out_size, void* d_ws, size_t ws_size,
                              hipStream_t stream) {
    const float* user_x     = (const float*)d_in[0];
    const float* job_x      = (const float*)d_in[1];
    const float* user_W     = (const float*)d_in[2];
    const float* user_b     = (const float*)d_in[3];
    const float* user_gamma = (const float*)d_in[4];
    const float* user_beta  = (const float*)d_in[5];
    const float* user_mean  = (const float*)d_in[6];
    const float* user_var   = (const float*)d_in[7];
    const float* job_W      = (const float*)d_in[8];
    const float* job_b      = (const float*)d_in[9];
    const float* job_gamma  = (const float*)d_in[10];
    const float* job_beta   = (const float*)d_in[11];
    const float* job_mean   = (const float*)d_in[12];
    const float* job_var    = (const float*)d_in[13];
    const float* l1_rates_Wl = (const float*)d_in[14];
    const float* l1_rates_Wr = (const float*)d_in[15];
    const float* l1_rev_Wl   = (const float*)d_in[16];
    const float* l1_rev_Wr   = (const float*)d_in[17];
    const float* l2_rates_Wl = (const float*)d_in[18];
    const float* l2_rates_Wr = (const float*)d_in[19];
    const float* l2_rev_Wl   = (const float*)d_in[20];
    const float* l2_rev_Wr   = (const float*)d_in[21];
    const float* l1_rates_bl = (const float*)d_in[22];
    const float* l1_rev_bl   = (const float*)d_in[23];
    const float* l2_rates_bl = (const float*)d_in[24];
    const float* l2_rev_bl   = (const float*)d_in[25];
    const int* rates_src = (const int*)d_in[26];
    const int* rates_dst = (const int*)d_in[27];
    const int* label_src = (const int*)d_in[28];
    const int* label_dst = (const int*)d_in[29];

    // ---- workspace layout ----
    char* ws = (char*)d_ws;
    size_t o = 0;
    auto alloc = [&](size_t bytes) -> void* {
        void* p = ws + o;
        o = (o + bytes + 511) & ~(size_t)511;
        return p;
    };
    unsigned short* u_bf = (unsigned short*)alloc((size_t)N_USERS * HID * 2);
    unsigned short* j_bf = (unsigned short*)alloc((size_t)N_JOBS  * HID * 2);
    unsigned short* u1   = (unsigned short*)alloc((size_t)N_USERS * HID * 2);
    unsigned short* j1   = (unsigned short*)alloc((size_t)N_JOBS  * HID * 2);
    unsigned short* aggU = (unsigned short*)alloc((size_t)N_USERS * HID * 2);
    unsigned short* aggJ = (unsigned short*)alloc((size_t)N_JOBS  * HID * 2);
    float* u2f = (float*)alloc((size_t)N_USERS * HID * 4);
    float* j2f = (float*)alloc((size_t)N_JOBS  * HID * 4);
    int* vals_j = (int*)alloc((size_t)N_EDGES * 4);
    int* vals_u = (int*)alloc((size_t)N_EDGES * 4);
    int* cnt_j  = (int*)alloc((size_t)N_JOBS * 4);
    int* cnt_u  = (int*)alloc((size_t)N_USERS * 4);
    int* off_j  = (int*)alloc((size_t)(N_JOBS + 1) * 4);
    int* off_u  = (int*)alloc((size_t)(N_USERS + 1) * 4);
    int* cur_j  = (int*)alloc((size_t)N_JOBS * 4);
    int* cur_u  = (int*)alloc((size_t)N_USERS * 4);
    int* part_j = (int*)alloc(256 * 4);
    int* part_u = (int*)alloc(256 * 4);
    (void)ws_size; (void)n_in; (void)in_sizes; (void)out_size;

    const int nbj = (N_JOBS + SCHUNK - 1) / SCHUNK;    // 49
    const int nbu = (N_USERS + SCHUNK - 1) / SCHUNK;   // 98

    // ---- CSR build (shared by both layers) ----
    hipMemsetAsync(cnt_j, 0, (size_t)N_JOBS * 4, stream);
    hipMemsetAsync(cnt_u, 0, (size_t)N_USERS * 4, stream);
    hist_kernel<<<2048, 256, 0, stream>>>(rates_src, rates_dst, N_EDGES, cnt_u, cnt_j);
    scan_blocksum<<<nbj, 256, 0, stream>>>(cnt_j, part_j, N_JOBS);
    scan_blocksum<<<nbu, 256, 0, stream>>>(cnt_u, part_u, N_USERS);
    scan_level2<<<2, 128, 0, stream>>>(part_j, nbj, part_u, nbu);
    scan_final<<<nbj, 256, 0, stream>>>(cnt_j, part_j, off_j, cur_j, N_JOBS);
    scan_final<<<nbu, 256, 0, stream>>>(cnt_u, part_u, off_u, cur_u, N_USERS);
    scatter_kernel<<<2048, 256, 0, stream>>>(rates_src, rates_dst, N_EDGES,
                                             cur_u, cur_j, vals_u, vals_j);

    // ---- encoders (bf16 MFMA) ----
    encoder_mfma<<<(N_USERS + 127) / 128, 256, 0, stream>>>(
        user_x, user_W, user_b, user_gamma, user_beta, user_mean, user_var, u_bf, N_USERS, 512);
    encoder_mfma<<<(N_JOBS + 127) / 128, 256, 0, stream>>>(
        job_x, job_W, job_b, job_gamma, job_beta, job_mean, job_var, j_bf, N_JOBS, 768);

    // ---- SAGE layer 1 (bf16 out, relu) ----
    aggregate_bf16<<<(N_JOBS + 3) / 4, 256, 0, stream>>>(u_bf, off_j, vals_j, aggJ, N_JOBS);
    sage_mfma<<<(N_JOBS + 127) / 128, 256, 0, stream>>>(
        aggJ, j_bf, l1_rates_Wl, l1_rates_Wr, l1_rates_bl, (void*)j1, N_JOBS, 1, 0);
    aggregate_bf16<<<(N_USERS + 3) / 4, 256, 0, stream>>>(j_bf, off_u, vals_u, aggU, N_USERS);
    sage_mfma<<<(N_USERS + 127) / 128, 256, 0, stream>>>(
        aggU, u_bf, l1_rev_Wl, l1_rev_Wr, l1_rev_bl, (void*)u1, N_USERS, 1, 0);

    // ---- SAGE layer 2 (fp32 out, no relu) ----
    aggregate_bf16<<<(N_JOBS + 3) / 4, 256, 0, stream>>>(u1, off_j, vals_j, aggJ, N_JOBS);
    sage_mfma<<<(N_JOBS + 127) / 128, 256, 0, stream>>>(
        aggJ, j1, l2_rates_Wl, l2_rates_Wr, l2_rates_bl, (void*)j2f, N_JOBS, 0, 1);
    aggregate_bf16<<<(N_USERS + 3) / 4, 256, 0, stream>>>(j1, off_u, vals_u, aggU, N_USERS);
    sage_mfma<<<(N_USERS + 127) / 128, 256, 0, stream>>>(
        aggU, u1, l2_rev_Wl, l2_rev_Wr, l2_rev_bl, (void*)u2f, N_USERS, 0, 1);

    // ---- link readout ----
    dot_kernel<<<(N_LABELS * 64 + 255) / 256, 256, 0, stream>>>(
        u2f, j2f, label_src, label_dst, (float*)d_out, N_LABELS);
}